// Round 10
// baseline (377.375 us; speedup 1.0000x reference)
//
#include <hip/hip_runtime.h>
#include <hip/hip_bf16.h>

typedef __bf16 bf16;
typedef __bf16 bf16x4 __attribute__((ext_vector_type(4)));
typedef __bf16 bf16x8 __attribute__((ext_vector_type(8)));
typedef float  f32x4  __attribute__((ext_vector_type(4)));
typedef float  f32x16 __attribute__((ext_vector_type(16)));
typedef unsigned u32x4 __attribute__((ext_vector_type(4)));
typedef __attribute__((address_space(3))) char lds_char;

#define SEQ  2048
#define HID  4096
#define QKVN 6144   // 4096 Q + 1024 K + 1024 V

__device__ __forceinline__ void gload_lds16(const void* g, void* l) {
  __builtin_amdgcn_global_load_lds(
      (const __attribute__((address_space(1))) void*)g,
      (__attribute__((address_space(3))) void*)l, 16, 0, 0);
}

// v_cvt_pk_bf16_f32: lo -> D[15:0], hi -> D[31:16] (RNE; no builtin on gfx950)
__device__ __forceinline__ unsigned cvtpk(float lo, float hi) {
  unsigned r;
  asm("v_cvt_pk_bf16_f32 %0, %1, %2" : "=v"(r) : "v"(lo), "v"(hi));
  return r;
}
__device__ __forceinline__ void plswap(unsigned& a, unsigned& b) {
  asm("v_permlane32_swap_b32 %0, %1" : "+v"(a), "+v"(b));
}

// ---------------- cast f32 -> bf16 (vectorized) ----------------
__global__ __launch_bounds__(256) void cast_f32_bf16(const float* __restrict__ in,
                                                     bf16* __restrict__ out, int n) {
  int i = (blockIdx.x * 256 + threadIdx.x) * 4;
  int stride = gridDim.x * 256 * 4;
  for (; i < n; i += stride) {
    float4 v = *(const float4*)(in + i);
    bf16x4 o;
    o[0] = (bf16)v.x; o[1] = (bf16)v.y; o[2] = (bf16)v.z; o[3] = (bf16)v.w;
    *(bf16x4*)(out + i) = o;
  }
}

// ---------------- transpose V out of QKV into global: Vt_g[g][d][s] ----------------
__global__ __launch_bounds__(256) void transpose_v(const bf16* __restrict__ QKV,
                                                   bf16* __restrict__ Vt_g) {
  __shared__ bf16 tile[32][33];
  int s0 = blockIdx.x * 32;
  int d0 = blockIdx.y * 32;
  int g  = blockIdx.z;
  int t = threadIdx.x;
  int r = t >> 5, c = t & 31;
#pragma unroll
  for (int p = 0; p < 4; ++p)
    tile[r + p * 8][c] = QKV[(size_t)(s0 + r + p * 8) * QKVN + 5120 + g * 128 + d0 + c];
  __syncthreads();
#pragma unroll
  for (int p = 0; p < 4; ++p)
    Vt_g[(size_t)(g * 128 + d0 + r + p * 8) * SEQ + s0 + c] = tile[c][r + p * 8];
}

// ======== 128x128 GEMM reading W in natural [K][N] f32 layout (T10 tr_read B-path) ========
// B LDS layout: subtiled [ks=k/4][ns=n/16] of 128B [4 k][16 n] row-major bf16 tiles.
// tr_read semantics (m156/m162, net-effect model): NO internal lane addressing — per-lane
// vaddr = subtile_base + (lane&15)*8 makes group g's 16 lanes read quarter-rows of ONE
// 4x16 subtile; HW shuffle hands lane c the column c (elems j = k ascending). Group term
// l4*2048 sends lane-group h to k-subtile ks=2h (B-frag needs k = h*8 + j). r9 bug: lane
// stride was *2 (overlapping bytes) — must be *8.
template <typename OUT_T>
__global__ __launch_bounds__(256) void gemm_trb(const bf16* __restrict__ A,
                                                const float* __restrict__ W0,
                                                const float* __restrict__ W1,
                                                const float* __restrict__ W2,
                                                OUT_T* __restrict__ C,
                                                int K, int ldc) {
  __shared__ __align__(16) bf16 Abuf[128 * 64];
  __shared__ __align__(16) bf16 Bbuf[64 * 128];   // subtiled [16 ks][8 ns][4][16]
  int m0 = blockIdx.y * 128, n0 = blockIdx.x * 128;
  const float* W; int Wn, n0l;
  if (n0 < 4096)      { W = W0; Wn = 4096; n0l = n0; }
  else if (n0 < 5120) { W = W1; Wn = 1024; n0l = n0 - 4096; }
  else                { W = W2; Wn = 1024; n0l = n0 - 5120; }
  int tid = threadIdx.x, w = tid >> 6, lane = tid & 63;
  int wr = w >> 1, wc = w & 1;
  int l15 = lane & 15, l4 = lane >> 4;
  f32x4 acc[4][4] = {};
  // per-lane tr_read base: addrspace(3) pointer (32-bit LDS offset in VGPR)
  lds_char* const bbase = (lds_char*)(char*)Bbuf + wc * 512 + l4 * 2048 + l15 * 8;
  const int nk = K >> 6;
  for (int kt = 0; kt < nk; ++kt) {
    int k0 = kt << 6;
    // ---- B: load f32 (8 consecutive n per chunk, 4 chunks/thread, coalesced) ----
    float4 bv0[4], bv1[4];
#pragma unroll
    for (int p = 0; p < 4; ++p) {
      int c = p * 256 + tid;
      int kq = c >> 4, n8 = (c & 15) * 8;
      const float* src = W + (size_t)(k0 + kq) * Wn + n0l + n8;
      bv0[p] = *(const float4*)src;
      bv1[p] = *(const float4*)(src + 4);
    }
    // ---- A: async global->LDS staging (proven path) ----
#pragma unroll
    for (int p = 0; p < 4; ++p) {
      int c = p * 256 + tid;
      int row = c >> 3, slot = c & 7;
      int ssl = (slot ^ (row & 7)) << 4;
      gload_lds16((const char*)(A + (size_t)(m0 + row) * K + k0) + ssl, (char*)Abuf + c * 16);
    }
    // ---- B: cvt_pk + subtiled ds_write_b128 ----
#pragma unroll
    for (int p = 0; p < 4; ++p) {
      int c = p * 256 + tid;
      int kq = c >> 4, n8 = (c & 15) * 8;
      u32x4 pw;
      pw[0] = cvtpk(bv0[p].x, bv0[p].y);
      pw[1] = cvtpk(bv0[p].z, bv0[p].w);
      pw[2] = cvtpk(bv1[p].x, bv1[p].y);
      pw[3] = cvtpk(bv1[p].z, bv1[p].w);
      int boff = (kq >> 2) * 1024 + (n8 >> 4) * 128 + (kq & 3) * 32 + (n8 & 15) * 2;
      *(u32x4*)((char*)Bbuf + boff) = pw;
    }
    __syncthreads();
    // ---- A frags (b128, swizzled; compiler-tracked) ----
    bf16x8 af[4][2];
#pragma unroll
    for (int m = 0; m < 4; ++m)
#pragma unroll
      for (int kk = 0; kk < 2; ++kk) {
        int row = wr * 64 + m * 16 + l15;
        af[m][kk] = *(const bf16x8*)((const char*)Abuf + row * 128 +
                                     (((kk * 4 + l4) ^ (row & 7)) << 4));
      }
    // ---- B frags via hardware transpose read ----
    unsigned long long tr[4][2][2];   // [nf][kk][h] — all static indexing
#pragma unroll
    for (int nf = 0; nf < 4; ++nf)
#pragma unroll
      for (int kk = 0; kk < 2; ++kk)
#pragma unroll
        for (int h = 0; h < 2; ++h)
          asm volatile("ds_read_b64_tr_b16 %0, %1 offset:%c2"
                       : "=v"(tr[nf][kk][h])
                       : "v"(bbase), "i"(kk * 8192 + h * 1024 + nf * 128));
    asm volatile("s_waitcnt lgkmcnt(0)" ::: "memory");
    __builtin_amdgcn_sched_barrier(0);   // rule #18: block MFMA hoisting past the wait
    bf16x8 bfr[4][2];
#pragma unroll
    for (int nf = 0; nf < 4; ++nf)
#pragma unroll
      for (int kk = 0; kk < 2; ++kk) {
        u32x4 pw;
        pw[0] = (unsigned)(tr[nf][kk][0]);
        pw[1] = (unsigned)(tr[nf][kk][0] >> 32);
        pw[2] = (unsigned)(tr[nf][kk][1]);
        pw[3] = (unsigned)(tr[nf][kk][1] >> 32);
        bfr[nf][kk] = __builtin_bit_cast(bf16x8, pw);
      }
#pragma unroll
    for (int kk = 0; kk < 2; ++kk)
#pragma unroll
      for (int m = 0; m < 4; ++m)
#pragma unroll
        for (int n = 0; n < 4; ++n)
          acc[m][n] = __builtin_amdgcn_mfma_f32_16x16x32_bf16(af[m][kk], bfr[n][kk],
                                                              acc[m][n], 0, 0, 0);
    __syncthreads();
  }
#pragma unroll
  for (int m = 0; m < 4; ++m)
#pragma unroll
    for (int n = 0; n < 4; ++n)
#pragma unroll
      for (int i = 0; i < 4; ++i) {
        int row = m0 + wr * 64 + m * 16 + l4 * 4 + i;
        int col = n0 + wc * 64 + n * 16 + l15;
        C[(size_t)row * ldc + col] = (OUT_T)acc[m][n][i];
      }
}

// ---------------- attention v6 (frozen from r8): 32x32 swapped-operand, in-reg softmax ----------------
__global__ __launch_bounds__(256, 2) void attn_kernel(const bf16* __restrict__ QKV,
                                                      const bf16* __restrict__ Vt_g,
                                                      bf16* __restrict__ attn) {
  __shared__ __align__(16) bf16 Klds[2][64 * 128];
  __shared__ __align__(16) bf16 Vlds[2][64 * 128];
  const int bid = blockIdx.x;
  const int g = bid & 7;
  const int rest = bid >> 3;
  const int hi = rest & 3;
  const int pair = rest >> 2;            // 0..15
  const int qb_a = pair, qb_b = 31 - pair;
  const int tid = threadIdx.x, w = tid >> 6, lane = tid & 63;
  const int l31 = lane & 31, hh = lane >> 5;
  const int head = g * 4 + hi;
  const bool isB = (w < 2);
  const int myqb = isB ? qb_b : qb_a;
  const int unit_q0 = myqb * 64 + (w & 1) * 32;
  const int qcol = head * 128;
  const int kcol = 4096 + g * 128;
  const float scale = 0.08838834764831845f;  // 1/sqrt(128)
  const float LOG2E = 1.4426950408889634f;

  const bf16* Vhead = Vt_g + (size_t)g * 128 * SEQ;

  bf16x8 qf[8];
#pragma unroll
  for (int db = 0; db < 8; ++db)
    qf[db] = *(const bf16x8*)(QKV + (size_t)(unit_q0 + l31) * QKVN + qcol +
                              db * 16 + hh * 8);

  f32x16 acc_o[4] = {};
  float m_run = -1e30f, l_run = 0.f;

  auto stageKV = [&](int kb, int buf) {
#pragma unroll
    for (int j = 0; j < 4; ++j) {
      int c = tid + (j << 8);
      int row = c >> 4, s = c & 15;
      int sl = s ^ (row & 15);
      gload_lds16((const char*)(QKV + (size_t)(kb + row) * QKVN + kcol) + (sl << 4),
                  (char*)Klds[buf] + (c << 4));
      int d = row * 2 + (sl >> 3);
      int ko = (sl & 7) << 3;
      gload_lds16(Vhead + (size_t)d * SEQ + kb + ko, (char*)Vlds[buf] + (c << 4));
    }
  };

  auto compute_unit = [&](int kb, int cur) {
    const char* Kb = (const char*)Klds[cur];
    const char* Vb = (const char*)Vlds[cur];
    f32x16 s0 = {}, s1 = {};
    __builtin_amdgcn_s_setprio(1);
#pragma unroll
    for (int db = 0; db < 8; ++db) {
      int slot = (db * 2 + hh) ^ (l31 & 15);
      bf16x8 k0 = *(const bf16x8*)(Kb + l31 * 256 + slot * 16);
      bf16x8 k1 = *(const bf16x8*)(Kb + (32 + l31) * 256 + slot * 16);
      s0 = __builtin_amdgcn_mfma_f32_32x32x16_bf16(k0, qf[db], s0, 0, 0, 0);
      s1 = __builtin_amdgcn_mfma_f32_32x32x16_bf16(k1, qf[db], s1, 0, 0, 0);
    }
    __builtin_amdgcn_s_setprio(0);
    float p0[16], p1[16];
    const bool needmask = (kb + 64 > unit_q0);
    const int qg = unit_q0 + l31;
#pragma unroll
    for (int r = 0; r < 16; ++r) {
      float v0 = s0[r] * scale, v1 = s1[r] * scale;
      if (needmask) {
        int krow = (r & 3) + 8 * (r >> 2) + 4 * hh;
        if (kb + krow > qg)      v0 = -1e30f;
        if (kb + 32 + krow > qg) v1 = -1e30f;
      }
      p0[r] = v0; p1[r] = v1;
    }
    float t = fmaxf(p0[0], p1[0]);
#pragma unroll
    for (int r = 1; r < 16; ++r) t = fmaxf(t, fmaxf(p0[r], p1[r]));
    t = fmaxf(t, __shfl_xor(t, 32));
    if (!__all(t - m_run <= 8.0f)) {
      float mnew = fmaxf(m_run, t);
      float fac = exp2f((m_run - mnew) * LOG2E);
      m_run = mnew;
      l_run *= fac;
#pragma unroll
      for (int dt = 0; dt < 4; ++dt)
#pragma unroll
        for (int r = 0; r < 16; ++r) acc_o[dt][r] *= fac;
    }
    float psum = 0.f;
#pragma unroll
    for (int r = 0; r < 16; ++r) {
      p0[r] = exp2f((p0[r] - m_run) * LOG2E); psum += p0[r];
      p1[r] = exp2f((p1[r] - m_run) * LOG2E); psum += p1[r];
    }
    psum += __shfl_xor(psum, 32);
    l_run += psum;
    bf16x8 paf[4];
#pragma unroll
    for (int kstep = 0; kstep < 4; ++kstep) {
      const float* p = (kstep < 2) ? p0 : p1;
      const int base = (kstep & 1) * 8;
      unsigned a0 = cvtpk(p[base + 0], p[base + 1]);
      unsigned b0 = cvtpk(p[base + 4], p[base + 5]);
      plswap(a0, b0);
      unsigned a1 = cvtpk(p[base + 2], p[base + 3]);
      unsigned b1 = cvtpk(p[base + 6], p[base + 7]);
      plswap(a1, b1);
      u32x4 pw; pw[0] = a0; pw[1] = a1; pw[2] = b0; pw[3] = b1;
      paf[kstep] = __builtin_bit_cast(bf16x8, pw);
    }
    __builtin_amdgcn_s_setprio(1);
#pragma unroll
    for (int dt = 0; dt < 4; ++dt) {
      int vrow = dt * 16 + (l31 >> 1);
#pragma unroll
      for (int kstep = 0; kstep < 4; ++kstep) {
        int slot = ((l31 & 1) * 8 + kstep * 2 + hh) ^ (vrow & 15);
        bf16x8 vf = *(const bf16x8*)(Vb + vrow * 256 + slot * 16);
        acc_o[dt] = __builtin_amdgcn_mfma_f32_32x32x16_bf16(vf, paf[kstep], acc_o[dt], 0, 0, 0);
      }
    }
    __builtin_amdgcn_s_setprio(0);
  };

  stageKV(0, 0);
  __syncthreads();

  int cur = 0;
  for (int kbi = 0; kbi <= qb_b; ++kbi) {
    int kb = kbi * 64;
    if (kbi < qb_b) stageKV(kb + 64, cur ^ 1);
    if (isB || kbi <= qb_a) compute_unit(kb, cur);
    __syncthreads();
    cur ^= 1;
  }

  float inv_l = 1.0f / l_run;
  bf16* orow = attn + (size_t)(unit_q0 + l31) * 4096 + qcol;
#pragma unroll
  for (int dt = 0; dt < 4; ++dt)
#pragma unroll
    for (int r = 0; r < 16; ++r) {
      int d = dt * 32 + (r & 3) + 8 * (r >> 2) + 4 * hh;
      orow[d] = (bf16)(acc_o[dt][r] * inv_l);
    }
}

extern "C" void kernel_launch(void* const* d_in, const int* in_sizes, int n_in,
                              void* d_out, int out_size, void* d_ws, size_t ws_size,
                              hipStream_t stream) {
  const float* X  = (const float*)d_in[0];
  const float* Wq = (const float*)d_in[1];
  const float* Wk = (const float*)d_in[2];
  const float* Wv = (const float*)d_in[3];
  const float* Wo = (const float*)d_in[4];
  float* out = (float*)d_out;

  // workspace: Xb 16.78MB | Vt_g 4.19MB | QKV 25.17MB = 46.14MB (Wt eliminated)
  const size_t XB_OFF  = 0;
  const size_t VT_OFF  = 16777216;
  const size_t QKV_OFF = 16777216 + 4194304;
  if (ws_size < (size_t)(QKV_OFF + 25165824)) return;

  char* ws = (char*)d_ws;
  bf16* Xb    = (bf16*)(ws + XB_OFF);
  bf16* Vt_g  = (bf16*)(ws + VT_OFF);
  bf16* QKV   = (bf16*)(ws + QKV_OFF);
  bf16* attnb = Xb;  // reuse after gemm1 consumed Xb

  // 1. cast hidden states
  cast_f32_bf16<<<2048, 256, 0, stream>>>(X, Xb, SEQ * HID);
  // 2. fused QKV projection reading Wq/Wk/Wv directly (f32 [K][N], tr_read B-path)
  gemm_trb<bf16><<<dim3(QKVN / 128, SEQ / 128), 256, 0, stream>>>(
      Xb, Wq, Wk, Wv, QKV, HID, QKVN);
  // 3. transpose V into global [g][d][s]
  transpose_v<<<dim3(SEQ / 32, 4, 8), 256, 0, stream>>>(QKV, Vt_g);
  // 4. causal GQA flash attention v6 (frozen)
  attn_kernel<<<512, 256, 0, stream>>>(QKV, Vt_g, attnb);
  // 5. output projection reading Wo directly -> f32 out
  gemm_trb<float><<<dim3(4096 / 128, SEQ / 128), 256, 0, stream>>>(
      attnb, Wo, Wo, Wo, out, HID, 4096);
}